// Round 4
// baseline (497.705 us; speedup 1.0000x reference)
//
#include <hip/hip_runtime.h>

// STDP learner: tr_pre/tr_post elementwise + delta_w = 0.5*w*(conv-wgrad pair).
// delta_w[o,i,kh,kw] = 0.5*w[o,i,kh,kw] *
//   sum_{b,p,q} tpre[b,i,p+kh,q+kw]*out[b,o,p,q] - tpost[b,o,p,q]*in[b,i,p+kh,q+kw]
// Sizes: B=16 CIN=64 H=W=66 COUT=128 HO=WO=64 KH=KW=3
// out layout: [tr_pre 4460544][tr_post 8388608][delta_w 73728]
//
// R4: R2's DMA+LDS structure (best so far) with occupancy fix:
//  - stage k=32 per barrier, mats interleaved in 8-chunk LDS rows (8-slot XOR
//    swizzle preserved -> 0 bank conflicts, verified R2)
//  - 8-row chunks, grid (128,2,9)=2304 blocks, 16KB LDS, launch_bounds(128,4)
//    => ~8-10 resident blocks/CU (vs R2's 4.5) to overlap barrier-drain stalls
//  - epilogue atomicAdd(0.5*w*acc) into dw; no partials, no finalize kernel

typedef unsigned short ushort_t;
typedef unsigned int uint_t;
typedef __attribute__((ext_vector_type(8))) short short8;
typedef __attribute__((ext_vector_type(4))) float floatx4;
typedef __attribute__((ext_vector_type(2))) float floatx2;

#define N_PRE   4460544      // 16*64*66*66
#define N_POST  8388608      // 16*128*64*64
#define N_DW    73728        // 128*64*9
#define O_TRPOST 4460544
#define O_DW     12849152
#define BSLICE   4325376     // per-kw shifted B copy: 16*64*66*64 elems

// async global->LDS, 16B/lane; global addr per-lane, LDS dst uniform+lane*16
#define GLDS16(g, l) __builtin_amdgcn_global_load_lds( \
    (const __attribute__((address_space(1))) void*)(g), \
    (__attribute__((address_space(3))) void*)(l), 16, 0, 0)

__device__ __forceinline__ ushort_t f2bf(float f) {
  uint_t u = __builtin_bit_cast(uint_t, f);
  u = (u + 0x7FFFu + ((u >> 16) & 1u)) >> 16;   // RNE
  return (ushort_t)u;
}

// ---- fused fill: [blocks 0..2112) pre+bfill, [2112..6208) post + A copies --
__global__ __launch_bounds__(256)
void k_fill(const float* __restrict__ in_sp, const float* __restrict__ out_sp,
            const float* __restrict__ tpre, const float* __restrict__ tpost,
            float* __restrict__ o_trpre, float* __restrict__ o_trpost,
            ushort_t* __restrict__ A1, ushort_t* __restrict__ A2,
            ushort_t* __restrict__ B1, ushort_t* __restrict__ B2, int use_ws) {
  int bx = blockIdx.x;
  if (bx < 2112) {
    // pre: thread = (row, q8), row = (b*64+i)*66+h over 67584 rows
    int tid = bx * 256 + threadIdx.x;                  // < 540672
    int row = tid >> 3, q8 = (tid & 7) * 8;
    int g = row * 66 + q8;                             // even -> 8B aligned
    float ftp[10], fin[10];
    #pragma unroll
    for (int k = 0; k < 5; ++k) {
      floatx2 a = *(const floatx2*)(tpre + g + 2 * k);
      floatx2 b = *(const floatx2*)(in_sp + g + 2 * k);
      ftp[2 * k] = a.x; ftp[2 * k + 1] = a.y;
      fin[2 * k] = b.x; fin[2 * k + 1] = b.y;
    }
    #pragma unroll
    for (int k = 0; k < 4; ++k) {
      floatx2 v = { 0.5f * ftp[2 * k] + fin[2 * k], 0.5f * ftp[2 * k + 1] + fin[2 * k + 1] };
      *(floatx2*)(o_trpre + g + 2 * k) = v;
    }
    if (q8 == 56) {                                    // tail cols 64,65
      floatx2 v = { 0.5f * ftp[8] + fin[8], 0.5f * ftp[9] + fin[9] };
      *(floatx2*)(o_trpre + row * 66 + 64) = v;
    }
    if (use_ws) {
      ushort_t utp[10], uin[10];
      #pragma unroll
      for (int k = 0; k < 10; ++k) { utp[k] = f2bf(ftp[k]); uin[k] = f2bf(fin[k]); }
      int dst = row * 64 + q8;                         // 16B aligned
      #pragma unroll
      for (int kw = 0; kw < 3; ++kw) {
        short8 v1, v2;
        #pragma unroll
        for (int k = 0; k < 8; ++k) { v1[k] = (short)utp[kw + k]; v2[k] = (short)uin[kw + k]; }
        *(short8*)(B1 + kw * BSLICE + dst) = v1;
        *(short8*)(B2 + kw * BSLICE + dst) = v2;
      }
    }
  } else {
    // post: elementwise tr_post + bf16 A copies
    int t8 = ((bx - 2112) * 256 + threadIdx.x) * 8;    // < N_POST
    floatx4 o0 = *(const floatx4*)(out_sp + t8);
    floatx4 o1 = *(const floatx4*)(out_sp + t8 + 4);
    floatx4 p0 = *(const floatx4*)(tpost + t8);
    floatx4 p1 = *(const floatx4*)(tpost + t8 + 4);
    *(floatx4*)(o_trpost + t8)     = 0.5f * p0 + o0;
    *(floatx4*)(o_trpost + t8 + 4) = 0.5f * p1 + o1;
    if (use_ws) {
      short8 va, vn;
      #pragma unroll
      for (int k = 0; k < 4; ++k) {
        va[k] = (short)f2bf(o0[k]); va[k + 4] = (short)f2bf(o1[k]);
        vn[k] = (short)f2bf(-p0[k]); vn[k + 4] = (short)f2bf(-p1[k]);
      }
      *(short8*)(A1 + t8) = va;
      *(short8*)(A2 + t8) = vn;
    }
  }
}

// ---- MFMA kernel: DMA-staged, high-occupancy, atomic epilogue --------------
// grid (128, 2, 9): x = k-chunk (8 (b,p) rows), y = o-half, z = e = kh*3+kw.
// block 128 = 2 waves; wave w computes o_local in [w*32, w*32+32) x 64 i.
// Per stage (k=32): wave0 DMAs A (both mats), wave1 DMAs B; 16 stages/block.
// LDS row (per o or i) = 8 slots of 16B; slot = (mat*4 + chunk) ^ (row&7).
__global__ __launch_bounds__(128, 4)
void k_mfma(const ushort_t* __restrict__ A1, const ushort_t* __restrict__ B1,
            const float* __restrict__ weight, float* __restrict__ dw) {
  __shared__ short LSA[4096];   // 64 o x 8 slots x 8 shorts = 8 KB
  __shared__ short LSB[4096];   // 64 i x 8 slots            = 8 KB

  const int e = blockIdx.z, kh = e / 3, kw = e - kh * 3;
  const int oh = blockIdx.y, cx = blockIdx.x;
  const int b = cx >> 3, p0 = (cx & 7) * 8;            // 8 rows, same b
  const int t = threadIdx.x, w = t >> 6, l = t & 63;
  const int quad = l >> 4, l16 = l & 15, wo = w * 32;

  // DMA lane decode: lds row lr, slot sc; stored (mat,chunk) = sc ^ lr
  const int lr = l >> 3, sc = l & 7;
  const int mc = sc ^ lr;
  const int mm = mc >> 2, cc = mc & 3;

  // per-lane global source bases (elements); instr j adds j*8 rows
  const ushort_t* ga = A1 + (size_t)b * 524288 + oh * 262144 + p0 * 64
                     + mm * 8388608 + lr * 4096 + cc * 8;
  const ushort_t* gb = B1 + (size_t)kw * BSLICE + (size_t)b * 270336 + (p0 + kh) * 64
                     + mm * 12976128 + lr * 4224 + cc * 8;   // B2-B1 = 3*BSLICE

  // precomputed LDS frag byte-offsets (constant per thread)
  int aoffs[2][2], boffs[2][4];
  #pragma unroll
  for (int mt = 0; mt < 2; ++mt) {
    const int o = wo + mt * 16 + l16;
    #pragma unroll
    for (int m2 = 0; m2 < 2; ++m2)
      aoffs[m2][mt] = (o * 8 + ((m2 * 4 + quad) ^ (o & 7))) * 8;
  }
  #pragma unroll
  for (int nt = 0; nt < 4; ++nt) {
    const int i = nt * 16 + l16;
    #pragma unroll
    for (int m2 = 0; m2 < 2; ++m2)
      boffs[m2][nt] = (i * 8 + ((m2 * 4 + quad) ^ (i & 7))) * 8;
  }

  floatx4 acc[2][4] = {};

  for (int s = 0; s < 16; ++s) {                       // 8 rows x 2 k-halves
    __syncthreads();                                   // prev compute done
    if (w == 0) {
      #pragma unroll
      for (int j = 0; j < 8; ++j)
        GLDS16(ga + s * 32 + j * 32768, LSA + j * 512);
    } else {
      #pragma unroll
      for (int j = 0; j < 8; ++j)
        GLDS16(gb + s * 32 + j * 33792, LSB + j * 512);
    }
    __syncthreads();                                   // DMA drained

    short8 fa[2][2], fb[2][4];
    #pragma unroll
    for (int mt = 0; mt < 2; ++mt)
      #pragma unroll
      for (int m2 = 0; m2 < 2; ++m2)
        fa[m2][mt] = *(const short8*)&LSA[aoffs[m2][mt]];
    #pragma unroll
    for (int nt = 0; nt < 4; ++nt)
      #pragma unroll
      for (int m2 = 0; m2 < 2; ++m2)
        fb[m2][nt] = *(const short8*)&LSB[boffs[m2][nt]];

    #pragma unroll
    for (int mt = 0; mt < 2; ++mt)
      #pragma unroll
      for (int nt = 0; nt < 4; ++nt) {
        acc[mt][nt] = __builtin_amdgcn_mfma_f32_16x16x32_bf16(fa[0][mt], fb[0][nt], acc[mt][nt], 0, 0, 0);
        acc[mt][nt] = __builtin_amdgcn_mfma_f32_16x16x32_bf16(fa[1][mt], fb[1][nt], acc[mt][nt], 0, 0, 0);
      }
  }

  // epilogue: dw += 0.5*w*acc (atomic; 128 contenders/elem; fp-order noise ~1e-6)
  // C/D layout: col(i)=lane&15, row(o within 16)=quad*4+reg (HW-verified)
  #pragma unroll
  for (int mt = 0; mt < 2; ++mt)
    #pragma unroll
    for (int nt = 0; nt < 4; ++nt)
      #pragma unroll
      for (int rg = 0; rg < 4; ++rg) {
        const int o = oh * 64 + wo + mt * 16 + quad * 4 + rg;
        const int i = nt * 16 + l16;
        const int wi = (o * 64 + i) * 9 + e;
        atomicAdd(&dw[wi], 0.5f * weight[wi] * acc[mt][nt][rg]);
      }
}

// ---- fallback (ws too small): slow fp32, zero scratch ----------------------
__global__ void k_naive(const float* __restrict__ out_sp, const float* __restrict__ tpost,
                        const float* __restrict__ tpre, const float* __restrict__ in_sp,
                        const float* __restrict__ weight, float* __restrict__ dw) {
  int tid = blockIdx.x * 256 + threadIdx.x;
  int e = tid >> 13, oi = tid & 8191;
  int o = oi >> 6, i = oi & 63;
  int kh = e / 3, kw = e - kh * 3;
  float acc = 0.f;
  for (int b = 0; b < 16; ++b)
    for (int p = 0; p < 64; ++p) {
      const float* ga = out_sp + ((b * 128 + o) * 64 + p) * 64;
      const float* gn = tpost + ((b * 128 + o) * 64 + p) * 64;
      const float* gb = tpre + ((b * 64 + i) * 66 + p + kh) * 66 + kw;
      const float* gm = in_sp + ((b * 64 + i) * 66 + p + kh) * 66 + kw;
      for (int q = 0; q < 64; ++q) acc += ga[q] * gb[q] - gn[q] * gm[q];
    }
  int wi = (o * 64 + i) * 9 + kh * 3 + kw;
  dw[wi] = 0.5f * weight[wi] * acc;
}

extern "C" void kernel_launch(void* const* d_in, const int* in_sizes, int n_in,
                              void* d_out, int out_size, void* d_ws, size_t ws_size,
                              hipStream_t stream) {
  const float* in_sp  = (const float*)d_in[0];
  const float* out_sp = (const float*)d_in[1];
  const float* tpre   = (const float*)d_in[2];
  const float* tpost  = (const float*)d_in[3];
  const float* weight = (const float*)d_in[4];
  float* out = (float*)d_out;
  float* o_trpre  = out;
  float* o_trpost = out + O_TRPOST;
  float* o_dw     = out + O_DW;

  // ws layout: A1 | A2 | B1(3 slices) | B2(3 slices)   (no partials)
  const size_t WS_NEED = 85458944;
  const int use_mfma = (ws_size >= WS_NEED) ? 1 : 0;
  ushort_t* A1 = (ushort_t*)d_ws;
  ushort_t* A2 = A1 + 8388608;
  ushort_t* B1 = A2 + 8388608;
  ushort_t* B2 = B1 + 3 * BSLICE;

  k_fill<<<6208, 256, 0, stream>>>(in_sp, out_sp, tpre, tpost,
                                   o_trpre, o_trpost, A1, A2, B1, B2, use_mfma);
  if (use_mfma) {
    hipMemsetAsync(o_dw, 0, N_DW * sizeof(float), stream);   // atomic target
    dim3 g(128, 2, 9);
    k_mfma<<<g, 128, 0, stream>>>(A1, B1, weight, o_dw);
    (void)A2; (void)B2;
  } else {
    k_naive<<<N_DW / 256, 256, 0, stream>>>(out_sp, tpost, tpre, in_sp, weight, o_dw);
  }
}

// Round 5
// 209.804 us; speedup vs baseline: 2.3722x; 2.3722x over previous
//
#include <hip/hip_runtime.h>

// STDP learner: tr_pre/tr_post elementwise + delta_w = 0.5*w*(conv-wgrad pair).
// delta_w[o,i,kh,kw] = 0.5*w[o,i,kh,kw] *
//   sum_{b,p,q} tpre[b,i,p+kh,q+kw]*out[b,o,p,q] - tpost[b,o,p,q]*in[b,i,p+kh,q+kw]
// Sizes: B=16 CIN=64 H=W=66 COUT=128 HO=WO=64 KH=KW=3
// out layout: [tr_pre 4460544][tr_post 8388608][delta_w 73728]
//
// R5: e-reuse to cut staged bytes (R2 was staging-BW-bound at ~12.7 TB/s):
//  - grid (128,3): z=kh; block = 4 waves x full o=128; 3 kw accumulated per
//    staged tile (24 acc tiles) -> A read 3x not 9x, B read 3x not 18x.
//  - B staged RAW (unshifted, 72-elem padded rows); kw-shifted fragments built
//    in registers: kw0/kw2 = register window, kw1 = 4 alignbit ops. Kills the
//    3-copy redundancy in k_fill AND k_mfma.
//  - A via global_load_lds + XOR swizzle (R2-proven, 0 conflicts); B via
//    dwordx4->ds_write into 304B-stride rows (2-way banks = free).
//  - partials + finalize epilogue (R4's atomics: WRITE_SIZE 295MB, 7.6x slower)

typedef unsigned short ushort_t;
typedef unsigned int uint_t;
typedef __attribute__((ext_vector_type(8))) short short8;
typedef __attribute__((ext_vector_type(4))) float floatx4;
typedef __attribute__((ext_vector_type(2))) float floatx2;
typedef __attribute__((ext_vector_type(4))) int intx4;

#define N_PRE   4460544      // 16*64*66*66
#define N_POST  8388608      // 16*128*64*64
#define N_DW    73728        // 128*64*9
#define O_TRPOST 4460544
#define O_DW     12849152
#define BROWS   67584        // (b*64+i)*66+h rows
#define BRAW    4866048      // 67584 * 72 elems per raw-B mat

// async global->LDS, 16B/lane; LDS dst = wave-uniform base + lane*16
#define GLDS16(g, l) __builtin_amdgcn_global_load_lds( \
    (const __attribute__((address_space(1))) void*)(g), \
    (__attribute__((address_space(3))) void*)(l), 16, 0, 0)

__device__ __forceinline__ ushort_t f2bf(float f) {
  uint_t u = __builtin_bit_cast(uint_t, f);
  u = (u + 0x7FFFu + ((u >> 16) & 1u)) >> 16;   // RNE
  return (ushort_t)u;
}

// bytes [2..5] of (hi:lo) -- one v_alignbit_b32
__device__ __forceinline__ int bsh2(int hi, int lo) {
  return (int)((((unsigned long long)(uint_t)hi << 32) | (uint_t)lo) >> 16);
}

// ---- fused fill ------------------------------------------------------------
// blocks [0..2376): tr_pre + raw bf16 B rows (72-elem padded stride)
// blocks [2376..6472): tr_post + bf16 A copies
__global__ __launch_bounds__(256)
void k_fill(const float* __restrict__ in_sp, const float* __restrict__ out_sp,
            const float* __restrict__ tpre, const float* __restrict__ tpost,
            float* __restrict__ o_trpre, float* __restrict__ o_trpost,
            ushort_t* __restrict__ A1, ushort_t* __restrict__ A2,
            ushort_t* __restrict__ B1, ushort_t* __restrict__ B2, int use_ws) {
  int bx = blockIdx.x;
  if (bx < 2376) {
    int tid = bx * 256 + threadIdx.x;                  // < 608256 = 67584*9
    int row = tid / 9, grp = tid - row * 9;
    int gcol = grp * 8;
    int g = row * 66 + gcol;
    float ftp[8] = {}, fin[8] = {};
    if (grp < 8) {
      #pragma unroll
      for (int k = 0; k < 4; ++k) {
        floatx2 a = *(const floatx2*)(tpre + g + 2 * k);
        floatx2 c = *(const floatx2*)(in_sp + g + 2 * k);
        ftp[2 * k] = a.x; ftp[2 * k + 1] = a.y;
        fin[2 * k] = c.x; fin[2 * k + 1] = c.y;
      }
      #pragma unroll
      for (int k = 0; k < 4; ++k) {
        floatx2 v = { 0.5f * ftp[2 * k] + fin[2 * k], 0.5f * ftp[2 * k + 1] + fin[2 * k + 1] };
        *(floatx2*)(o_trpre + g + 2 * k) = v;
      }
    } else {                                           // cols 64,65 only
      floatx2 a = *(const floatx2*)(tpre + g);
      floatx2 c = *(const floatx2*)(in_sp + g);
      ftp[0] = a.x; ftp[1] = a.y; fin[0] = c.x; fin[1] = c.y;
      floatx2 v = { 0.5f * ftp[0] + fin[0], 0.5f * ftp[1] + fin[1] };
      *(floatx2*)(o_trpre + g) = v;
    }
    if (use_ws) {
      short8 v1, v2;
      #pragma unroll
      for (int k = 0; k < 8; ++k) { v1[k] = (short)f2bf(ftp[k]); v2[k] = (short)f2bf(fin[k]); }
      *(short8*)(B1 + row * 72 + gcol) = v1;           // pad cols = garbage, never read
      *(short8*)(B2 + row * 72 + gcol) = v2;
    }
  } else {
    int t8 = ((bx - 2376) * 256 + threadIdx.x) * 8;    // < N_POST
    floatx4 o0 = *(const floatx4*)(out_sp + t8);
    floatx4 o1 = *(const floatx4*)(out_sp + t8 + 4);
    floatx4 p0 = *(const floatx4*)(tpost + t8);
    floatx4 p1 = *(const floatx4*)(tpost + t8 + 4);
    *(floatx4*)(o_trpost + t8)     = 0.5f * p0 + o0;
    *(floatx4*)(o_trpost + t8 + 4) = 0.5f * p1 + o1;
    if (use_ws) {
      short8 va, vn;
      #pragma unroll
      for (int k = 0; k < 4; ++k) {
        va[k] = (short)f2bf(o0[k]); va[k + 4] = (short)f2bf(o1[k]);
        vn[k] = (short)f2bf(-p0[k]); vn[k + 4] = (short)f2bf(-p1[k]);
      }
      *(short8*)(A1 + t8) = va;
      *(short8*)(A2 + t8) = vn;
    }
  }
}

// ---- MFMA kernel: kh-block, 3-kw accumulate, raw-B register shift ----------
// grid (128, 3): x -> (b = x>>3, p0 = (x&7)*8), y = kh. block 256 = 4 waves,
// wave w owns o in [w*32, w*32+32). Per stage (one p-row, k=64):
//   waves 0,1: DMA A (both mats, 128 o) into XOR-swizzled LDS (32 KB)
//   waves 2,3: load raw B row h=p+kh (both mats) -> ds_write padded rows
// LA layout: [o][ks][slot8]x16B, slot = (mat*4+chunk)^(o&7)  (2-way = free)
// LB layout: [i][mat*9+ch9]x16B, row stride 304B              (2-way = free)
__global__ __launch_bounds__(256, 2)
void k_mfma(const ushort_t* __restrict__ A1, const ushort_t* __restrict__ B1,
            float* __restrict__ partials) {
  __shared__ short LA[16384];          // 32 KB
  __shared__ short LB[64 * 152];       // 19 KB (304B rows)

  const int kh = blockIdx.y, bx = blockIdx.x;
  const int b = bx >> 3, p0 = (bx & 7) * 8;
  const int t = threadIdx.x, w = t >> 6, l = t & 63;
  const int quad = l >> 4, l16 = l & 15;

  // A-DMA decode (waves 0,1): chunk c = w*1024 + j*64 + l
  //   o = w*64 + j*4 + (l>>4); g=(l>>3)&1; slot=l&7
  //   stored (mat,c4) = slot ^ (o&7); o&7 = ((j&1)<<2) ^ (l>>4)
  const int lr = l >> 4;
  const int gA = (l >> 3) & 1;
  const int mcE = (l & 7) ^ lr;                        // j even
  const int matE = mcE >> 2, c4E = mcE & 3;
  const long aoffE = (long)matE * 8388608 + (long)(w & 1) * 262144
                   + lr * 4096 + gA * 32 + c4E * 8;
  const long aoffO = aoffE + (matE ? -8388608L : 8388608L);  // j odd: mat flips, c4 same

  const int t2 = t & 127;                              // B-stage thread id

  floatx4 acc[3][2][4] = {};                           // [kw][mt][nt]

  for (int rr = 0; rr < 8; ++rr) {
    const int p = p0 + rr, h = p + kh;
    __syncthreads();                                   // prev compute done
    if (w < 2) {
      const ushort_t* ga = A1 + (long)b * 524288 + p * 64;
      #pragma unroll
      for (int j = 0; j < 16; ++j) {
        const ushort_t* src = ga + ((j & 1) ? aoffO : aoffE) + j * 16384;
        GLDS16(src, LA + (w & 1) * 8192 + j * 512);
      }
    } else {
      const ushort_t* gb = B1 + ((long)b * 4224 + h) * 72;
      #pragma unroll
      for (int k = 0; k < 9; ++k) {
        int c = k * 128 + t2;                          // < 1152
        int i = c / 18, mc = c - i * 18;
        int mat = (mc >= 9) ? 1 : 0, ch9 = mc - mat * 9;
        intx4 v = *(const intx4*)(gb + (long)mat * BRAW + i * 4752 + ch9 * 8);
        *(intx4*)&LB[i * 152 + mat * 72 + ch9 * 8] = v;
      }
    }
    __syncthreads();                                   // staging drained

    #pragma unroll
    for (int ks = 0; ks < 2; ++ks) {
      short8 fa[2][2];                                 // [mat][mt]
      #pragma unroll
      for (int mt = 0; mt < 2; ++mt) {
        const int o = w * 32 + mt * 16 + l16;
        #pragma unroll
        for (int mat = 0; mat < 2; ++mat)
          fa[mat][mt] = *(const short8*)&LA[o * 128 + ks * 64 + (((mat << 2) + quad) ^ (o & 7)) * 8];
      }
      #pragma unroll
      for (int nt = 0; nt < 4; ++nt) {
        const int i = nt * 16 + l16;
        short8 fb[2][3];                               // [mat][kw]
        #pragma unroll
        for (int mat = 0; mat < 2; ++mat) {
          const int base = i * 152 + mat * 72 + ks * 32 + quad * 8;
          intx4 W = *(const intx4*)&LB[base];
          int W4 = *(const int*)&LB[base + 8];
          intx4 f0 = { W.x, W.y, W.z, W.w };
          intx4 f1 = { bsh2(W.y, W.x), bsh2(W.z, W.y), bsh2(W.w, W.z), bsh2(W4, W.w) };
          intx4 f2 = { W.y, W.z, W.w, W4 };
          fb[mat][0] = __builtin_bit_cast(short8, f0);
          fb[mat][1] = __builtin_bit_cast(short8, f1);
          fb[mat][2] = __builtin_bit_cast(short8, f2);
        }
        #pragma unroll
        for (int kw = 0; kw < 3; ++kw)
          #pragma unroll
          for (int mt = 0; mt < 2; ++mt) {
            acc[kw][mt][nt] = __builtin_amdgcn_mfma_f32_16x16x32_bf16(fa[0][mt], fb[0][kw], acc[kw][mt][nt], 0, 0, 0);
            acc[kw][mt][nt] = __builtin_amdgcn_mfma_f32_16x16x32_bf16(fa[1][mt], fb[1][kw], acc[kw][mt][nt], 0, 0, 0);
          }
      }
    }
  }

  // C/D layout: col(i)=lane&15, row(o within 16)=quad*4+reg (HW-verified)
  #pragma unroll
  for (int kw = 0; kw < 3; ++kw) {
    float* slice = partials + (size_t)((kh * 3 + kw) * 128 + bx) * 8192;
    #pragma unroll
    for (int mt = 0; mt < 2; ++mt)
      #pragma unroll
      for (int nt = 0; nt < 4; ++nt)
        #pragma unroll
        for (int rg = 0; rg < 4; ++rg) {
          const int o = w * 32 + mt * 16 + quad * 4 + rg;
          const int i = nt * 16 + l16;
          slice[o * 64 + i] = acc[kw][mt][nt][rg];
        }
  }
}

// ---- split-K reduction + finalize ------------------------------------------
__global__ void k_finalize(const float* __restrict__ partials,
                           const float* __restrict__ weight, float* __restrict__ dw) {
  int tid = blockIdx.x * 256 + threadIdx.x;            // < 73728
  int e = tid >> 13, oi = tid & 8191;
  float s = 0.f;
  #pragma unroll 8
  for (int c = 0; c < 128; ++c) s += partials[(size_t)(e * 128 + c) * 8192 + oi];
  int o = oi >> 6, i = oi & 63;
  int wi = (o * 64 + i) * 9 + e;
  dw[wi] = 0.5f * weight[wi] * s;
}

// ---- fallback (ws too small): slow fp32, zero scratch ----------------------
__global__ void k_naive(const float* __restrict__ out_sp, const float* __restrict__ tpost,
                        const float* __restrict__ tpre, const float* __restrict__ in_sp,
                        const float* __restrict__ weight, float* __restrict__ dw) {
  int tid = blockIdx.x * 256 + threadIdx.x;
  int e = tid >> 13, oi = tid & 8191;
  int o = oi >> 6, i = oi & 63;
  int kh = e / 3, kw = e - kh * 3;
  float acc = 0.f;
  for (int b = 0; b < 16; ++b)
    for (int p = 0; p < 64; ++p) {
      const float* ga = out_sp + ((b * 128 + o) * 64 + p) * 64;
      const float* gn = tpost + ((b * 128 + o) * 64 + p) * 64;
      const float* gb = tpre + ((b * 64 + i) * 66 + p + kh) * 66 + kw;
      const float* gm = in_sp + ((b * 64 + i) * 66 + p + kh) * 66 + kw;
      for (int q = 0; q < 64; ++q) acc += ga[q] * gb[q] - gn[q] * gm[q];
    }
  int wi = (o * 64 + i) * 9 + kh * 3 + kw;
  dw[wi] = 0.5f * weight[wi] * acc;
}

extern "C" void kernel_launch(void* const* d_in, const int* in_sizes, int n_in,
                              void* d_out, int out_size, void* d_ws, size_t ws_size,
                              hipStream_t stream) {
  const float* in_sp  = (const float*)d_in[0];
  const float* out_sp = (const float*)d_in[1];
  const float* tpre   = (const float*)d_in[2];
  const float* tpost  = (const float*)d_in[3];
  const float* weight = (const float*)d_in[4];
  float* out = (float*)d_out;
  float* o_trpre  = out;
  float* o_trpost = out + O_TRPOST;
  float* o_dw     = out + O_DW;

  // ws: A1 | A2 (bf16 16.8MB ea) | B1raw | B2raw (9.7MB ea) | partials 37.7MB
  const size_t WS_NEED = 90767360;
  const int use_mfma = (ws_size >= WS_NEED) ? 1 : 0;
  ushort_t* A1 = (ushort_t*)d_ws;
  ushort_t* A2 = A1 + 8388608;
  ushort_t* B1 = A2 + 8388608;
  ushort_t* B2 = B1 + BRAW;
  float* partials = (float*)(B2 + BRAW);

  k_fill<<<6472, 256, 0, stream>>>(in_sp, out_sp, tpre, tpost,
                                   o_trpre, o_trpost, A1, A2, B1, B2, use_mfma);
  if (use_mfma) {
    dim3 g(128, 3);
    k_mfma<<<g, 256, 0, stream>>>(A1, B1, partials);
    k_finalize<<<N_DW / 256, 256, 0, stream>>>(partials, weight, o_dw);
  } else {
    k_naive<<<N_DW / 256, 256, 0, stream>>>(out_sp, tpost, tpre, in_sp, weight, o_dw);
  }
}